// Round 2
// baseline (1769.700 us; speedup 1.0000x reference)
//
#include <hip/hip_runtime.h>

#define D       256
#define NHEADS  8
#define DH      32
#define FFDIM   1024
#define VOCAB   2048
#define GENLEN  16
#define BATCH   8
#define NSLOT   7
#define TF      17
#define NLAYER  4

struct Params {
  // inputs
  const float *slots, *W_slot_proj, *dict_emb, *pe;
  const float *ln_self_w, *ln_self_b, *Wq_s, *Wk_s, *Wv_s, *Wo_s;
  const float *ln_cross_w, *ln_cross_b, *Wq_c, *Wk_c, *Wv_c, *Wo_c;
  const float *ln_ffn_w, *ln_ffn_b, *W1, *b1, *W2, *b2;
  const float *ln_f_w, *ln_f_b, *W_out;
  // workspace
  float *enc, *Kc, *Vc, *kcache, *vcache, *logits;
  // outputs
  float *out_z, *out_lp;
};

__device__ __forceinline__ float blockSum(float v, float* red) {
  #pragma unroll
  for (int o = 32; o > 0; o >>= 1) v += __shfl_down(v, o);
  const int lane = threadIdx.x & 63, w = threadIdx.x >> 6;
  if (lane == 0) red[w] = v;
  __syncthreads();
  float s = red[0] + red[1] + red[2] + red[3];
  __syncthreads();
  return s;
}

// ---------------- init: enc = slots @ W_slot_proj ----------------
__global__ __launch_bounds__(256) void enc_kernel(Params p) {
  const int b = blockIdx.x, tid = threadIdx.x;
  __shared__ float ssh[NSLOT * D];
  for (int i = tid; i < NSLOT * D; i += 256) ssh[i] = p.slots[b * NSLOT * D + i];
  __syncthreads();
  float acc[NSLOT] = {0.f, 0.f, 0.f, 0.f, 0.f, 0.f, 0.f};
  for (int i = 0; i < D; ++i) {
    const float w = p.W_slot_proj[i * D + tid];
    #pragma unroll
    for (int s = 0; s < NSLOT; ++s) acc[s] += ssh[s * D + i] * w;
  }
  for (int s = 0; s < NSLOT; ++s) p.enc[(b * NSLOT + s) * D + tid] = acc[s];
}

// ---------------- init: Kc/Vc = enc @ Wk_c / Wv_c ----------------
__global__ __launch_bounds__(256) void kvc_kernel(Params p) {
  const int l = blockIdx.x >> 3, b = blockIdx.x & 7, tid = threadIdx.x;
  __shared__ float esh[NSLOT * D];
  for (int i = tid; i < NSLOT * D; i += 256) esh[i] = p.enc[b * NSLOT * D + i];
  __syncthreads();
  float ak[NSLOT] = {0.f,0.f,0.f,0.f,0.f,0.f,0.f};
  float av[NSLOT] = {0.f,0.f,0.f,0.f,0.f,0.f,0.f};
  const float* Wk = p.Wk_c + l * D * D;
  const float* Wv = p.Wv_c + l * D * D;
  for (int i = 0; i < D; ++i) {
    const float wk = Wk[i * D + tid];
    const float wv = Wv[i * D + tid];
    #pragma unroll
    for (int s = 0; s < NSLOT; ++s) { ak[s] += esh[s * D + i] * wk; av[s] += esh[s * D + i] * wv; }
  }
  for (int s = 0; s < NSLOT; ++s) {
    p.Kc[((l * BATCH + b) * NSLOT + s) * D + tid] = ak[s];
    p.Vc[((l * BATCH + b) * NSLOT + s) * D + tid] = av[s];
  }
}

// ---- self-attention stage: fold -> LN -> QKV(head) -> attn -> Wo rows -> partial ----
// layer 0 additionally: argmax(prev logits) -> outputs for step t-1 -> embedding
__global__ __launch_bounds__(256) void self_kernel(Params p, int layer, int t,
    const float* __restrict__ Pread, float* __restrict__ Pwrite,
    const float* __restrict__ xread, float* __restrict__ xwrite)
{
  const int b = blockIdx.x >> 3, hd = blockIdx.x & 7, tid = threadIdx.x;
  __shared__ float hsh[D], qsh[DH], osh[DH], score[TF], red[4];
  __shared__ float sval[256];
  __shared__ int   sidx[256];

  float xv;
  if (layer == 0) {
    int tok = 0;
    if (t > 0) {
      const float* lg = p.logits + b * VOCAB;
      float m = -1e30f; int mi = 0;
      for (int c = tid; c < VOCAB; c += 256) { float v = lg[c]; if (v > m) { m = v; mi = c; } }
      sval[tid] = m; sidx[tid] = mi;
      __syncthreads();
      for (int s = 128; s; s >>= 1) {
        if (tid < s) {
          float v2 = sval[tid + s]; int i2 = sidx[tid + s];
          if (v2 > sval[tid] || (v2 == sval[tid] && i2 < sidx[tid])) { sval[tid] = v2; sidx[tid] = i2; }
        }
        __syncthreads();
      }
      const float mx = sval[0]; const int amax = sidx[0];
      __syncthreads();
      float ssum = 0.f;
      for (int c = tid; c < VOCAB; c += 256) ssum += expf(lg[c] - mx);
      const float tot = blockSum(ssum, red);
      const float lse = mx + logf(tot);
      // write log-softmax slice for step t-1 (cols hd*256 .. hd*256+255)
      p.out_lp[(b * GENLEN + (t - 1)) * VOCAB + hd * 256 + tid] = lg[hd * 256 + tid] - lse;
      if (hd == 0 && tid == 0)
        p.out_z[b * VOCAB * GENLEN + amax * GENLEN + (t - 1)] = 1.0f;
      tok = amax + 1;  // BOS column prepended in buffer
    }
    xv = p.dict_emb[tok * D + tid] + p.pe[t * D + tid];
  } else {
    xv = xread[b * D + tid];
    #pragma unroll
    for (int i = 0; i < 8; ++i) xv += Pread[(b * 8 + i) * D + tid];
  }

  // LayerNorm (self)
  const float mean = blockSum(xv, red) * (1.f / D);
  const float dv = xv - mean;
  const float var = blockSum(dv * dv, red) * (1.f / D);
  const float hval = dv * (1.f / sqrtf(var + 1e-5f)) * p.ln_self_w[layer * D + tid]
                   + p.ln_self_b[layer * D + tid];
  hsh[tid] = hval;
  // SLATE quirk: layer 0 replaces residual stream with LN output
  if (hd == 0) xwrite[b * D + tid] = (layer == 0) ? hval : xv;
  __syncthreads();

  // q,k,v for this head: threads 0..95, 32 cols per matrix
  if (tid < 96) {
    const int mm = tid >> 5, c32 = tid & 31, c = hd * DH + c32;
    const float* W = (mm == 0 ? p.Wq_s : (mm == 1 ? p.Wk_s : p.Wv_s)) + layer * D * D + c;
    float a0 = 0.f, a1 = 0.f, a2 = 0.f, a3 = 0.f;
    for (int i = 0; i < D; i += 4) {
      a0 += hsh[i]     * W[i * D];
      a1 += hsh[i + 1] * W[(i + 1) * D];
      a2 += hsh[i + 2] * W[(i + 2) * D];
      a3 += hsh[i + 3] * W[(i + 3) * D];
    }
    const float acc = (a0 + a1) + (a2 + a3);
    if (mm == 0)      qsh[c32] = acc * 0.17677669529663689f;   // dh^-0.5
    else if (mm == 1) p.kcache[((layer * BATCH + b) * TF + t) * D + c] = acc;
    else              p.vcache[((layer * BATCH + b) * TF + t) * D + c] = acc;
  }
  __syncthreads();

  // scores over positions 0..t
  if (tid <= t) {
    const float* kk = p.kcache + ((layer * BATCH + b) * TF + tid) * D + hd * DH;
    float acc = 0.f;
    #pragma unroll
    for (int r = 0; r < DH; ++r) acc += qsh[r] * kk[r];
    score[tid] = acc;
  }
  __syncthreads();
  if (tid == 0) {
    float mx = -1e30f;
    for (int i = 0; i <= t; ++i) mx = fmaxf(mx, score[i]);
    float s2 = 0.f;
    for (int i = 0; i <= t; ++i) { const float e = expf(score[i] - mx); score[i] = e; s2 += e; }
    const float inv = 1.f / s2;
    for (int i = 0; i <= t; ++i) score[i] *= inv;
  }
  __syncthreads();
  if (tid < DH) {
    float acc = 0.f;
    for (int pp = 0; pp <= t; ++pp)
      acc += score[pp] * p.vcache[((layer * BATCH + b) * TF + pp) * D + hd * DH + tid];
    osh[tid] = acc;
  }
  __syncthreads();

  // Wo row-slice (rows hd*32..hd*32+31) -> partial contribution to all 256 cols
  {
    const float* Wo = p.Wo_s + layer * D * D + hd * DH * D + tid;
    float a0 = 0.f;
    #pragma unroll
    for (int r = 0; r < DH; ++r) a0 += osh[r] * Wo[r * D];
    Pwrite[(b * 8 + hd) * D + tid] = a0;
  }
}

// ---- cross-attention stage ----
__global__ __launch_bounds__(256) void cross_kernel(Params p, int layer,
    const float* __restrict__ Pread, float* __restrict__ Pwrite,
    const float* __restrict__ xread, float* __restrict__ xwrite)
{
  const int b = blockIdx.x >> 3, hd = blockIdx.x & 7, tid = threadIdx.x;
  __shared__ float hsh[D], qsh[DH], osh[DH], score[NSLOT + 1], red[4];
  float xv = xread[b * D + tid];
  #pragma unroll
  for (int i = 0; i < 8; ++i) xv += Pread[(b * 8 + i) * D + tid];
  if (hd == 0) xwrite[b * D + tid] = xv;

  const float mean = blockSum(xv, red) * (1.f / D);
  const float dv = xv - mean;
  const float var = blockSum(dv * dv, red) * (1.f / D);
  hsh[tid] = dv * (1.f / sqrtf(var + 1e-5f)) * p.ln_cross_w[layer * D + tid]
           + p.ln_cross_b[layer * D + tid];
  __syncthreads();

  if (tid < DH) {
    const int c = hd * DH + tid;
    const float* W = p.Wq_c + layer * D * D + c;
    float a0 = 0.f, a1 = 0.f, a2 = 0.f, a3 = 0.f;
    for (int i = 0; i < D; i += 4) {
      a0 += hsh[i]     * W[i * D];
      a1 += hsh[i + 1] * W[(i + 1) * D];
      a2 += hsh[i + 2] * W[(i + 2) * D];
      a3 += hsh[i + 3] * W[(i + 3) * D];
    }
    qsh[tid] = ((a0 + a1) + (a2 + a3)) * 0.17677669529663689f;
  }
  __syncthreads();
  if (tid < NSLOT) {
    const float* kk = p.Kc + ((layer * BATCH + b) * NSLOT + tid) * D + hd * DH;
    float acc = 0.f;
    #pragma unroll
    for (int r = 0; r < DH; ++r) acc += qsh[r] * kk[r];
    score[tid] = acc;
  }
  __syncthreads();
  if (tid == 0) {
    float mx = -1e30f;
    for (int i = 0; i < NSLOT; ++i) mx = fmaxf(mx, score[i]);
    float s2 = 0.f;
    for (int i = 0; i < NSLOT; ++i) { const float e = expf(score[i] - mx); score[i] = e; s2 += e; }
    const float inv = 1.f / s2;
    for (int i = 0; i < NSLOT; ++i) score[i] *= inv;
  }
  __syncthreads();
  if (tid < DH) {
    float acc = 0.f;
    #pragma unroll
    for (int s = 0; s < NSLOT; ++s)
      acc += score[s] * p.Vc[((layer * BATCH + b) * NSLOT + s) * D + hd * DH + tid];
    osh[tid] = acc;
  }
  __syncthreads();
  const float* Wo = p.Wo_c + layer * D * D + hd * DH * D + tid;
  float a0 = 0.f;
  #pragma unroll
  for (int r = 0; r < DH; ++r) a0 += osh[r] * Wo[r * D];
  Pwrite[(b * 8 + hd) * D + tid] = a0;
}

// ---- FFN stage: fold -> LN -> W1 cols (128) -> relu -> W2 rows (128) -> partial ----
__global__ __launch_bounds__(256) void ffn_kernel(Params p, int layer,
    const float* __restrict__ Pread, float* __restrict__ Pwrite,
    const float* __restrict__ xread, float* __restrict__ xwrite)
{
  const int b = blockIdx.x >> 3, sl = blockIdx.x & 7, tid = threadIdx.x;
  __shared__ float hsh[D], ash[128], red[4];
  float xv = xread[b * D + tid];
  #pragma unroll
  for (int i = 0; i < 8; ++i) xv += Pread[(b * 8 + i) * D + tid];
  if (sl == 0) xwrite[b * D + tid] = xv;

  const float mean = blockSum(xv, red) * (1.f / D);
  const float dv = xv - mean;
  const float var = blockSum(dv * dv, red) * (1.f / D);
  hsh[tid] = dv * (1.f / sqrtf(var + 1e-5f)) * p.ln_ffn_w[layer * D + tid]
           + p.ln_ffn_b[layer * D + tid];
  __syncthreads();

  if (tid < 128) {
    const int c = sl * 128 + tid;
    const float* W = p.W1 + layer * D * FFDIM + c;
    float a0 = 0.f, a1 = 0.f, a2 = 0.f, a3 = 0.f;
    for (int i = 0; i < D; i += 4) {
      a0 += hsh[i]     * W[i * FFDIM];
      a1 += hsh[i + 1] * W[(i + 1) * FFDIM];
      a2 += hsh[i + 2] * W[(i + 2) * FFDIM];
      a3 += hsh[i + 3] * W[(i + 3) * FFDIM];
    }
    const float acc = ((a0 + a1) + (a2 + a3)) + p.b1[layer * FFDIM + c];
    ash[tid] = fmaxf(acc, 0.f);
  }
  __syncthreads();

  float acc = (sl == 0) ? p.b2[layer * D + tid] : 0.f;
  const float* W2 = p.W2 + layer * FFDIM * D + sl * 128 * D + tid;
  for (int r = 0; r < 128; ++r) acc += ash[r] * W2[r * D];
  Pwrite[(b * 8 + sl) * D + tid] = acc;
}

// ---- logits stage: fold -> ln_f -> W_out slice (256 cols) ----
__global__ __launch_bounds__(256) void logits_kernel(Params p,
    const float* __restrict__ Pread, const float* __restrict__ xread)
{
  const int b = blockIdx.x >> 3, sl = blockIdx.x & 7, tid = threadIdx.x;
  __shared__ float hsh[D], red[4];
  float xv = xread[b * D + tid];
  #pragma unroll
  for (int i = 0; i < 8; ++i) xv += Pread[(b * 8 + i) * D + tid];
  const float mean = blockSum(xv, red) * (1.f / D);
  const float dv = xv - mean;
  const float var = blockSum(dv * dv, red) * (1.f / D);
  hsh[tid] = dv * (1.f / sqrtf(var + 1e-5f)) * p.ln_f_w[tid] + p.ln_f_b[tid];
  __syncthreads();
  const int c = sl * 256 + tid;
  const float* W = p.W_out + c;
  float a0 = 0.f, a1 = 0.f, a2 = 0.f, a3 = 0.f;
  for (int i = 0; i < D; i += 4) {
    a0 += hsh[i]     * W[i * VOCAB];
    a1 += hsh[i + 1] * W[(i + 1) * VOCAB];
    a2 += hsh[i + 2] * W[(i + 2) * VOCAB];
    a3 += hsh[i + 3] * W[(i + 3) * VOCAB];
  }
  p.logits[b * VOCAB + c] = (a0 + a1) + (a2 + a3);
}

// ---- final output writes for step t = GENLEN-1 ----
__global__ __launch_bounds__(256) void finalout_kernel(Params p) {
  const int b = blockIdx.x >> 3, sl = blockIdx.x & 7, tid = threadIdx.x;
  __shared__ float sval[256], red[4];
  __shared__ int sidx[256];
  const float* lg = p.logits + b * VOCAB;
  float m = -1e30f; int mi = 0;
  for (int c = tid; c < VOCAB; c += 256) { float v = lg[c]; if (v > m) { m = v; mi = c; } }
  sval[tid] = m; sidx[tid] = mi;
  __syncthreads();
  for (int s = 128; s; s >>= 1) {
    if (tid < s) {
      float v2 = sval[tid + s]; int i2 = sidx[tid + s];
      if (v2 > sval[tid] || (v2 == sval[tid] && i2 < sidx[tid])) { sval[tid] = v2; sidx[tid] = i2; }
    }
    __syncthreads();
  }
  const float mx = sval[0]; const int amax = sidx[0];
  __syncthreads();
  float ssum = 0.f;
  for (int c = tid; c < VOCAB; c += 256) ssum += expf(lg[c] - mx);
  const float tot = blockSum(ssum, red);
  const float lse = mx + logf(tot);
  p.out_lp[(b * GENLEN + (GENLEN - 1)) * VOCAB + sl * 256 + tid] = lg[sl * 256 + tid] - lse;
  if (sl == 0 && tid == 0)
    p.out_z[b * VOCAB * GENLEN + amax * GENLEN + (GENLEN - 1)] = 1.0f;
}

extern "C" void kernel_launch(void* const* d_in, const int* in_sizes, int n_in,
                              void* d_out, int out_size, void* d_ws, size_t ws_size,
                              hipStream_t stream)
{
  Params p;
  const float* const* in = (const float* const*)d_in;
  p.slots = in[0];  p.W_slot_proj = in[1]; p.dict_emb = in[2]; p.pe = in[3];
  p.ln_self_w = in[4];  p.ln_self_b = in[5];
  p.Wq_s = in[6];  p.Wk_s = in[7];  p.Wv_s = in[8];  p.Wo_s = in[9];
  p.ln_cross_w = in[10]; p.ln_cross_b = in[11];
  p.Wq_c = in[12]; p.Wk_c = in[13]; p.Wv_c = in[14]; p.Wo_c = in[15];
  p.ln_ffn_w = in[16]; p.ln_ffn_b = in[17];
  p.W1 = in[18]; p.b1 = in[19]; p.W2 = in[20]; p.b2 = in[21];
  p.ln_f_w = in[22]; p.ln_f_b = in[23]; p.W_out = in[24];

  float* ws = (float*)d_ws;
  p.enc = ws;    ws += BATCH * NSLOT * D;                 // 14336
  p.Kc = ws;     ws += NLAYER * BATCH * NSLOT * D;        // 57344
  p.Vc = ws;     ws += NLAYER * BATCH * NSLOT * D;        // 57344
  p.kcache = ws; ws += NLAYER * BATCH * TF * D;           // 139264
  p.vcache = ws; ws += NLAYER * BATCH * TF * D;           // 139264
  float* X0 = ws; ws += BATCH * D;
  float* X1 = ws; ws += BATCH * D;
  float* P0 = ws; ws += BATCH * 8 * D;
  float* P1 = ws; ws += BATCH * 8 * D;
  p.logits = ws;  ws += BATCH * VOCAB;

  p.out_z = (float*)d_out;
  p.out_lp = (float*)d_out + BATCH * VOCAB * GENLEN;

  // zero the one-hot region (log-probs are fully overwritten)
  hipMemsetAsync(d_out, 0, (size_t)out_size * sizeof(float), stream);

  enc_kernel<<<BATCH, 256, 0, stream>>>(p);
  kvc_kernel<<<NLAYER * BATCH, 256, 0, stream>>>(p);

  float* X[2] = {X0, X1};
  float* P[2] = {P0, P1};
  int par = 0;
  for (int t = 0; t < GENLEN; ++t) {
    for (int l = 0; l < NLAYER; ++l) {
      self_kernel<<<64, 256, 0, stream>>>(p, l, t, P[par], P[par ^ 1], X[par], X[par ^ 1]); par ^= 1;
      cross_kernel<<<64, 256, 0, stream>>>(p, l, P[par], P[par ^ 1], X[par], X[par ^ 1]);   par ^= 1;
      ffn_kernel<<<64, 256, 0, stream>>>(p, l, P[par], P[par ^ 1], X[par], X[par ^ 1]);     par ^= 1;
    }
    logits_kernel<<<64, 256, 0, stream>>>(p, P[par], X[par]);
  }
  finalout_kernel<<<64, 256, 0, stream>>>(p);
}